// Round 4
// baseline (170.109 us; speedup 1.0000x reference)
//
#include <hip/hip_runtime.h>

typedef __attribute__((ext_vector_type(4))) float f32x4;
typedef __attribute__((ext_vector_type(8))) short s16x8;
typedef __attribute__((ext_vector_type(4))) unsigned int u32x4;

// float -> bf16 bits, round-nearest-even
__device__ __forceinline__ unsigned int f2bf(float f) {
  unsigned int u = __float_as_uint(f);
  u += 0x7fffu + ((u >> 16) & 1u);
  return u >> 16;
}
// bf16 (packed in dword) -> float
__device__ __forceinline__ float bf_lo(unsigned int p) { return __uint_as_float(p << 16); }
__device__ __forceinline__ float bf_hi(unsigned int p) { return __uint_as_float(p & 0xffff0000u); }

// ---------------------------------------------------------------------------
// Kernel A: transpose x NCHW fp32 [8][128][64][64] -> NHWC bf16 xt[b][p][c]
// (p = y*64+x linear position, c innermost: 256 B per position).
// Reads fully coalesced; writes 16 B/lane at 256 B stride (1-2 us total).
// ---------------------------------------------------------------------------
__global__ __launch_bounds__(256) void xtrans_kernel(const float* __restrict__ x,
                                                     unsigned short* __restrict__ xt) {
  int t = blockIdx.x * 256 + threadIdx.x;   // 0..524287
  int p  = t & 4095;
  int cg = (t >> 12) & 15;
  int b  = t >> 16;
  const float* xp = x + (((size_t)(b * 128 + cg * 8)) << 12) + p;
  unsigned int r[8];
#pragma unroll
  for (int j = 0; j < 8; ++j) r[j] = f2bf(xp[(size_t)j << 12]);
  u32x4 pk;
  pk.x = r[0] | (r[1] << 16);
  pk.y = r[2] | (r[3] << 16);
  pk.z = r[4] | (r[5] << 16);
  pk.w = r[6] | (r[7] << 16);
  *reinterpret_cast<u32x4*>(xt + ((((size_t)b << 12) + p) << 7) + cg * 8) = pk;
}

// ---------------------------------------------------------------------------
// Kernel B: repack weight [128][128][3][3] fp32 -> bf16 MFMA A-fragments for
// v_mfma_f32_16x16x32_bf16:
//   wf[((ch*8 + mt)*64 + lane)*8 + j] = bf16(W[mt*16+(lane&15)]
//                                            [cc*32 + (lane>>4)*8 + j][tap])
// ch = cc*9 + tap. 294912 B.
// ---------------------------------------------------------------------------
__global__ __launch_bounds__(256) void wtrans_kernel(const float* __restrict__ w,
                                                     unsigned short* __restrict__ wf) {
  int tid = blockIdx.x * 256 + threadIdx.x;   // 0..18431
  int l  = tid & 63;
  int mt = (tid >> 6) & 7;
  int ch = tid >> 9;                          // 0..35
  int cc = ch / 9, tap = ch - cc * 9;
  int co = mt * 16 + (l & 15);
  int cb = cc * 32 + (l >> 4) * 8;
  unsigned int r[8];
#pragma unroll
  for (int j = 0; j < 8; ++j)
    r[j] = f2bf(w[(co * 128 + cb + j) * 9 + tap]);
  u32x4 pk;
  pk.x = r[0] | (r[1] << 16);
  pk.y = r[2] | (r[3] << 16);
  pk.z = r[4] | (r[5] << 16);
  pk.w = r[6] | (r[7] << 16);
  *reinterpret_cast<u32x4*>(wf + (size_t)tid * 8) = pk;
}

// ---------------------------------------------------------------------------
// Main kernel, round 4: barrier-free wave-private gather->MFMA (R3 structure)
// with NHWC-bf16 gather. Lane (ln,kg) gathers channels kg*8+0..7 (16 B,
// contiguous) at position 16w+ln; the quarter-wave's 4 kg groups share one
// 64 B line -> 4 gather instrs x 16 lines per chunk (vs 16 x 64 in NCHW).
// Separable bilinear with validity folded into 4 weights; 4 16-B loads per
// channel-chunk (TL, TR, BL, BR). b = bid&7 keeps xt XCD-affine.
// ---------------------------------------------------------------------------
__global__ __launch_bounds__(256, 2) void deform_kernel(const unsigned short* __restrict__ xt,
                                                        const float* __restrict__ off,
                                                        const unsigned short* __restrict__ wf,
                                                        float* __restrict__ out) {
  __shared__ int2   sPos[576];   // [tap*64+wo] row0/row1 base position indices
  __shared__ float4 sWt[576];    // [tap*64+wo] folded bilinear weights

  const int tid = threadIdx.x;
  const int bid = blockIdx.x;
  const int b  = bid & 7;        // XCD-affine batch
  const int ho = bid >> 3;

  for (int r = tid; r < 576; r += 256) {
    int tap = r >> 6, wo = r & 63;
    float dy = off[((b * 18 + 2 * tap)     * 64 + ho) * 64 + wo];
    float dx = off[((b * 18 + 2 * tap + 1) * 64 + ho) * 64 + wo];
    float py = (float)(ho + (tap / 3) - 1) + dy;
    float px = (float)(wo + (tap % 3) - 1) + dx;
    float fy = floorf(py), fx = floorf(px);
    int y0 = (int)fy, x0 = (int)fx;
    float wy = py - fy, wx = px - fx;
    float wt = (y0 >= 0 && y0 < 64) ? (1.f - wy) : 0.f;
    float wb = (y0 + 1 >= 0 && y0 + 1 < 64) ? wy : 0.f;
    int y0c = min(max(y0, 0), 63), y1c = min(max(y0 + 1, 0), 63);
    int bx; float wl, wr;
    if (x0 >= 0 && x0 <= 62)      { bx = x0; wl = 1.f - wx; wr = wx;       }
    else if (x0 == -1)            { bx = 0;  wl = wx;       wr = 0.f;      }
    else if (x0 == 63)            { bx = 62; wl = 0.f;      wr = 1.f - wx; }
    else                          { bx = 0;  wl = 0.f;      wr = 0.f;      }
    sPos[r] = make_int2(y0c * 64 + bx, y1c * 64 + bx);
    sWt[r]  = make_float4(wt * wl, wt * wr, wb * wl, wb * wr);
  }
  __syncthreads();   // the ONLY barrier

  const int w  = tid >> 6;        // wave -> wo base 16w
  const int ln = tid & 15;
  const int kg = (tid >> 4) & 3;  // k-group (8 consecutive channels)
  const int wo = w * 16 + ln;

  const unsigned short* xtb = xt + ((size_t)b << 19) + kg * 8;  // b*4096*128
  const unsigned short* wfb = wf + (size_t)(tid & 63) * 8;

  f32x4 acc[8] = {};

  for (int cc = 0; cc < 4; ++cc) {
    const int cof = cc * 32;
#pragma unroll
    for (int tap = 0; tap < 9; ++tap) {
      const int ch = cc * 9 + tap;
      const int2   a  = sPos[tap * 64 + wo];
      const float4 wv = sWt[tap * 64 + wo];

      // 4 x 16B gathers: 8 channels at TL, TR, BL, BR
      const unsigned short* p0 = xtb + ((size_t)a.x << 7) + cof;
      const unsigned short* p1 = xtb + ((size_t)a.y << 7) + cof;
      u32x4 T0, T1, B0, B1;
      __builtin_memcpy(&T0, p0,       16);
      __builtin_memcpy(&T1, p0 + 128, 16);
      __builtin_memcpy(&B0, p1,       16);
      __builtin_memcpy(&B1, p1 + 128, 16);

      // unpack + interpolate (fp32) + pack -> this lane's B-fragment
      u32x4 pk;
#pragma unroll
      for (int d = 0; d < 4; ++d) {
        float vl = wv.x * bf_lo(T0[d]) + wv.y * bf_lo(T1[d])
                 + wv.z * bf_lo(B0[d]) + wv.w * bf_lo(B1[d]);
        float vh = wv.x * bf_hi(T0[d]) + wv.y * bf_hi(T1[d])
                 + wv.z * bf_hi(B0[d]) + wv.w * bf_hi(B1[d]);
        pk[d] = f2bf(vl) | (f2bf(vh) << 16);
      }
      s16x8 bfrag;
      __builtin_memcpy(&bfrag, &pk, 16);

      // A-fragments (coalesced 16B/lane, L1-resident across waves) + MFMA
      const unsigned short* wp = wfb + (size_t)(ch * 8) * 64 * 8;
#pragma unroll
      for (int mt = 0; mt < 8; ++mt) {
        s16x8 afrag = *reinterpret_cast<const s16x8*>(wp + (size_t)mt * 64 * 8);
        acc[mt] = __builtin_amdgcn_mfma_f32_16x16x32_bf16(afrag, bfrag, acc[mt], 0, 0, 0);
      }
    }
  }

  // epilogue: C/D layout col = lane&15, row = (lane>>4)*4 + reg
#pragma unroll
  for (int mt = 0; mt < 8; ++mt)
#pragma unroll
    for (int rg = 0; rg < 4; ++rg) {
      int co = mt * 16 + kg * 4 + rg;
      out[((b * 128 + co) * 64 + ho) * 64 + wo] = acc[mt][rg];
    }
}

extern "C" void kernel_launch(void* const* d_in, const int* in_sizes, int n_in,
                              void* d_out, int out_size, void* d_ws, size_t ws_size,
                              hipStream_t stream) {
  (void)in_sizes; (void)n_in; (void)out_size; (void)ws_size;
  const float* x   = (const float*)d_in[0];
  const float* off = (const float*)d_in[1];
  const float* w   = (const float*)d_in[2];
  float* out = (float*)d_out;
  unsigned short* xt = (unsigned short*)d_ws;                 // 8388608 B
  unsigned short* wf = (unsigned short*)d_ws + (8388608 / 2); // 294912 B

  xtrans_kernel<<<2048, 256, 0, stream>>>(x, xt);
  wtrans_kernel<<<72, 256, 0, stream>>>(w, wf);
  deform_kernel<<<512, 256, 0, stream>>>(xt, off, wf, out);
}

// Round 5
// 122.268 us; speedup vs baseline: 1.3913x; 1.3913x over previous
//
#include <hip/hip_runtime.h>

typedef __attribute__((ext_vector_type(4))) float f32x4;
typedef __attribute__((ext_vector_type(8))) short s16x8;
typedef __attribute__((ext_vector_type(4))) unsigned int u32x4;

// float -> bf16 bits, round-nearest-even
__device__ __forceinline__ unsigned int f2bf(float f) {
  unsigned int u = __float_as_uint(f);
  u += 0x7fffu + ((u >> 16) & 1u);
  return u >> 16;
}
// bf16 (packed in dword) -> float
__device__ __forceinline__ float bf_lo(unsigned int p) { return __uint_as_float(p << 16); }
__device__ __forceinline__ float bf_hi(unsigned int p) { return __uint_as_float(p & 0xffff0000u); }

// ---------------------------------------------------------------------------
// Kernel A: transpose x NCHW fp32 [8][128][64][64] -> NHWC bf16 xt[b][p][c]
// (p = y*64+x, c innermost: 256 B per position record).
// ---------------------------------------------------------------------------
__global__ __launch_bounds__(256) void xtrans_kernel(const float* __restrict__ x,
                                                     unsigned short* __restrict__ xt) {
  int t = blockIdx.x * 256 + threadIdx.x;   // 0..524287
  int p  = t & 4095;
  int cg = (t >> 12) & 15;
  int b  = t >> 16;
  const float* xp = x + (((size_t)(b * 128 + cg * 8)) << 12) + p;
  unsigned int r[8];
#pragma unroll
  for (int j = 0; j < 8; ++j) r[j] = f2bf(xp[(size_t)j << 12]);
  u32x4 pk;
  pk.x = r[0] | (r[1] << 16);
  pk.y = r[2] | (r[3] << 16);
  pk.z = r[4] | (r[5] << 16);
  pk.w = r[6] | (r[7] << 16);
  *reinterpret_cast<u32x4*>(xt + ((((size_t)b << 12) + p) << 7) + cg * 8) = pk;
}

// ---------------------------------------------------------------------------
// Kernel B: repack weight [128][128][3][3] fp32 -> bf16 MFMA A-fragments for
// v_mfma_f32_16x16x32_bf16 (unchanged, verified R2-R4):
//   wf[((ch*8 + mt)*64 + lane)*8 + j] = bf16(W[mt*16+(lane&15)]
//                                            [cc*32 + (lane>>4)*8 + j][tap])
// ch = cc*9 + tap. 294912 B.
// ---------------------------------------------------------------------------
__global__ __launch_bounds__(256) void wtrans_kernel(const float* __restrict__ w,
                                                     unsigned short* __restrict__ wf) {
  int tid = blockIdx.x * 256 + threadIdx.x;   // 0..18431
  int l  = tid & 63;
  int mt = (tid >> 6) & 7;
  int ch = tid >> 9;                          // 0..35
  int cc = ch / 9, tap = ch - cc * 9;
  int co = mt * 16 + (l & 15);
  int cb = cc * 32 + (l >> 4) * 8;
  unsigned int r[8];
#pragma unroll
  for (int j = 0; j < 8; ++j)
    r[j] = f2bf(w[(co * 128 + cb + j) * 9 + tap]);
  u32x4 pk;
  pk.x = r[0] | (r[1] << 16);
  pk.y = r[2] | (r[3] << 16);
  pk.z = r[4] | (r[5] << 16);
  pk.w = r[6] | (r[7] << 16);
  *reinterpret_cast<u32x4*>(wf + (size_t)tid * 8) = pk;
}

// ---------------------------------------------------------------------------
// Main kernel, round 5: fat wave tiles + in-block K-split.
// Block = (b, ho), 4 waves. Wave ks owns channel slab cc = ks (taps 0..8) and
// computes the FULL row tile: 64 wo x 128 Cout partial sums. Per chunk a wave
// issues 8 A-loads + 16 gathers = 24 VMEM for 32 MFMAs (R4: 12 VMEM / 8
// MFMA). Total VMEM instrs halve: 885K -> 442K; per-lane TA throughput is the
// measured bottleneck (~1 addr/cyc/CU). Epilogue: serial LDS tree-reduce of
// the 4 partials (33 KB buffer, 6 barriers) then wave 0 stores.
// No barriers in the K-loop. b = bid&7 keeps xt XCD-affine.
// ---------------------------------------------------------------------------
__global__ __launch_bounds__(256, 2) void deform_kernel(const unsigned short* __restrict__ xt,
                                                        const float* __restrict__ off,
                                                        const unsigned short* __restrict__ wf,
                                                        float* __restrict__ out) {
  __shared__ int2   sPos[576];        // [tap*64+wo] row0/row1 position indices
  __shared__ float4 sWt[576];         // [tap*64+wo] folded bilinear weights
  __shared__ float  sRed[64 * 132];   // reduce buffer [wo][co], pad 132

  const int tid = threadIdx.x;
  const int bid = blockIdx.x;
  const int b  = bid & 7;             // XCD-affine batch
  const int ho = bid >> 3;

  for (int r = tid; r < 576; r += 256) {
    int tap = r >> 6, wo = r & 63;
    float dy = off[((b * 18 + 2 * tap)     * 64 + ho) * 64 + wo];
    float dx = off[((b * 18 + 2 * tap + 1) * 64 + ho) * 64 + wo];
    float py = (float)(ho + (tap / 3) - 1) + dy;
    float px = (float)(wo + (tap % 3) - 1) + dx;
    float fy = floorf(py), fx = floorf(px);
    int y0 = (int)fy, x0 = (int)fx;
    float wy = py - fy, wx = px - fx;
    float wt = (y0 >= 0 && y0 < 64) ? (1.f - wy) : 0.f;
    float wb = (y0 + 1 >= 0 && y0 + 1 < 64) ? wy : 0.f;
    int y0c = min(max(y0, 0), 63), y1c = min(max(y0 + 1, 0), 63);
    int bx; float wl, wr;
    if (x0 >= 0 && x0 <= 62)      { bx = x0; wl = 1.f - wx; wr = wx;       }
    else if (x0 == -1)            { bx = 0;  wl = wx;       wr = 0.f;      }
    else if (x0 == 63)            { bx = 62; wl = 0.f;      wr = 1.f - wx; }
    else                          { bx = 0;  wl = 0.f;      wr = 0.f;      }
    sPos[r] = make_int2(y0c * 64 + bx, y1c * 64 + bx);
    sWt[r]  = make_float4(wt * wl, wt * wr, wb * wl, wb * wr);
  }
  __syncthreads();

  const int l  = tid & 63;
  const int ks = tid >> 6;        // wave -> channel slab cc = ks
  const int ln = l & 15;
  const int kg = l >> 4;          // k-group (8 consecutive channels)

  // lane's channel base inside the 256-B position record: ks*32 + kg*8
  const unsigned short* xtb = xt + ((size_t)b << 19) + ks * 32 + kg * 8;
  const unsigned short* wfb = wf + (size_t)l * 8;

  f32x4 acc[4][8] = {};   // [pos-group][m-tile] -> 128 VGPRs

  for (int tap = 0; tap < 9; ++tap) {
    const int ch = ks * 9 + tap;

    // A-fragments once per chunk, reused across 4 pos-groups
    s16x8 A[8];
    const unsigned short* wp = wfb + (size_t)(ch * 8) * 512;
#pragma unroll
    for (int mt = 0; mt < 8; ++mt)
      A[mt] = *reinterpret_cast<const s16x8*>(wp + (size_t)mt * 512);

#pragma unroll
    for (int pg = 0; pg < 4; ++pg) {
      const int wo = pg * 16 + ln;
      const int2   a  = sPos[tap * 64 + wo];
      const float4 wv = sWt[tap * 64 + wo];

      const unsigned short* p0 = xtb + ((size_t)a.x << 7);
      const unsigned short* p1 = xtb + ((size_t)a.y << 7);
      u32x4 T0, T1, B0, B1;
      __builtin_memcpy(&T0, p0,       16);
      __builtin_memcpy(&T1, p0 + 128, 16);
      __builtin_memcpy(&B0, p1,       16);
      __builtin_memcpy(&B1, p1 + 128, 16);

      u32x4 pk;
#pragma unroll
      for (int d = 0; d < 4; ++d) {
        float vl = wv.x * bf_lo(T0[d]) + wv.y * bf_lo(T1[d])
                 + wv.z * bf_lo(B0[d]) + wv.w * bf_lo(B1[d]);
        float vh = wv.x * bf_hi(T0[d]) + wv.y * bf_hi(T1[d])
                 + wv.z * bf_hi(B0[d]) + wv.w * bf_hi(B1[d]);
        pk[d] = f2bf(vl) | (f2bf(vh) << 16);
      }
      s16x8 bfrag;
      __builtin_memcpy(&bfrag, &pk, 16);

#pragma unroll
      for (int mt = 0; mt < 8; ++mt)
        acc[pg][mt] = __builtin_amdgcn_mfma_f32_16x16x32_bf16(A[mt], bfrag, acc[pg][mt], 0, 0, 0);
    }
  }

  // ---- epilogue: serial LDS tree-reduce of the 4 K-partials ----
  // C/D layout: wo = pg*16 + ln, co = mt*16 + kg*4 + reg (reg 0..3 contig).
#define WR_LDS                                                                 \
  { _Pragma("unroll") for (int pg = 0; pg < 4; ++pg)                           \
    _Pragma("unroll") for (int mt = 0; mt < 8; ++mt)                           \
      *reinterpret_cast<f32x4*>(&sRed[(pg * 16 + ln) * 132 + mt * 16 + kg * 4]) = acc[pg][mt]; }
#define RD_LDS                                                                 \
  { _Pragma("unroll") for (int pg = 0; pg < 4; ++pg)                           \
    _Pragma("unroll") for (int mt = 0; mt < 8; ++mt) {                         \
      f32x4 v = *reinterpret_cast<const f32x4*>(&sRed[(pg * 16 + ln) * 132 + mt * 16 + kg * 4]); \
      acc[pg][mt] += v; } }

  __syncthreads();
  if (ks == 1) WR_LDS
  __syncthreads();
  if (ks == 0) RD_LDS
  __syncthreads();
  if (ks == 3) WR_LDS
  __syncthreads();
  if (ks == 2) RD_LDS
  __syncthreads();
  if (ks == 2) WR_LDS
  __syncthreads();
  if (ks == 0) {
    RD_LDS
#pragma unroll
    for (int pg = 0; pg < 4; ++pg)
#pragma unroll
      for (int mt = 0; mt < 8; ++mt)
#pragma unroll
        for (int rg = 0; rg < 4; ++rg) {
          int co = mt * 16 + kg * 4 + rg;
          out[((b * 128 + co) * 64 + ho) * 64 + pg * 16 + ln] = acc[pg][mt][rg];
        }
  }
#undef WR_LDS
#undef RD_LDS
}

extern "C" void kernel_launch(void* const* d_in, const int* in_sizes, int n_in,
                              void* d_out, int out_size, void* d_ws, size_t ws_size,
                              hipStream_t stream) {
  (void)in_sizes; (void)n_in; (void)out_size; (void)ws_size;
  const float* x   = (const float*)d_in[0];
  const float* off = (const float*)d_in[1];
  const float* w   = (const float*)d_in[2];
  float* out = (float*)d_out;
  unsigned short* xt = (unsigned short*)d_ws;                 // 8388608 B
  unsigned short* wf = (unsigned short*)d_ws + (8388608 / 2); // 294912 B

  xtrans_kernel<<<2048, 256, 0, stream>>>(x, xt);
  wtrans_kernel<<<72, 256, 0, stream>>>(w, wf);
  deform_kernel<<<512, 256, 0, stream>>>(xt, off, wf, out);
}

// Round 6
// 121.744 us; speedup vs baseline: 1.3973x; 1.0043x over previous
//
#include <hip/hip_runtime.h>

typedef __attribute__((ext_vector_type(4))) float f32x4;
typedef __attribute__((ext_vector_type(8))) short s16x8;
typedef __attribute__((ext_vector_type(4))) unsigned int u32x4;

// float -> bf16 bits, round-nearest-even
__device__ __forceinline__ unsigned int f2bf(float f) {
  unsigned int u = __float_as_uint(f);
  u += 0x7fffu + ((u >> 16) & 1u);
  return u >> 16;
}
// bf16 (packed in dword) -> float
__device__ __forceinline__ float bf_lo(unsigned int p) { return __uint_as_float(p << 16); }
__device__ __forceinline__ float bf_hi(unsigned int p) { return __uint_as_float(p & 0xffff0000u); }

// ---------------------------------------------------------------------------
// Kernel A: transpose x NCHW fp32 [8][128][64][64] -> NHWC bf16 xt[b][p][c]
// (p = y*64+x, c innermost: 256 B per position record).
// ---------------------------------------------------------------------------
__global__ __launch_bounds__(256) void xtrans_kernel(const float* __restrict__ x,
                                                     unsigned short* __restrict__ xt) {
  int t = blockIdx.x * 256 + threadIdx.x;   // 0..524287
  int p  = t & 4095;
  int cg = (t >> 12) & 15;
  int b  = t >> 16;
  const float* xp = x + (((size_t)(b * 128 + cg * 8)) << 12) + p;
  unsigned int r[8];
#pragma unroll
  for (int j = 0; j < 8; ++j) r[j] = f2bf(xp[(size_t)j << 12]);
  u32x4 pk;
  pk.x = r[0] | (r[1] << 16);
  pk.y = r[2] | (r[3] << 16);
  pk.z = r[4] | (r[5] << 16);
  pk.w = r[6] | (r[7] << 16);
  *reinterpret_cast<u32x4*>(xt + ((((size_t)b << 12) + p) << 7) + cg * 8) = pk;
}

// ---------------------------------------------------------------------------
// Kernel B: repack weight [128][128][3][3] fp32 -> bf16 MFMA A-fragments
// (unchanged, verified R2-R5):
//   wf[((ch*8 + mt)*64 + lane)*8 + j] = bf16(W[mt*16+(lane&15)]
//                                            [cc*32 + (lane>>4)*8 + j][tap])
// ch = cc*9 + tap. 294912 B.
// ---------------------------------------------------------------------------
__global__ __launch_bounds__(256) void wtrans_kernel(const float* __restrict__ w,
                                                     unsigned short* __restrict__ wf) {
  int tid = blockIdx.x * 256 + threadIdx.x;   // 0..18431
  int l  = tid & 63;
  int mt = (tid >> 6) & 7;
  int ch = tid >> 9;                          // 0..35
  int cc = ch / 9, tap = ch - cc * 9;
  int co = mt * 16 + (l & 15);
  int cb = cc * 32 + (l >> 4) * 8;
  unsigned int r[8];
#pragma unroll
  for (int j = 0; j < 8; ++j)
    r[j] = f2bf(w[(co * 128 + cb + j) * 9 + tap]);
  u32x4 pk;
  pk.x = r[0] | (r[1] << 16);
  pk.y = r[2] | (r[3] << 16);
  pk.z = r[4] | (r[5] << 16);
  pk.w = r[6] | (r[7] << 16);
  *reinterpret_cast<u32x4*>(wf + (size_t)tid * 8) = pk;
}

// ---------------------------------------------------------------------------
// Main kernel, round 6: R5 structure + LDS WINDOW STAGING for gathers.
// Measured law: ~64 cyc per wave64 VMEM instr regardless of coalescing (TA
// ~1 lane-addr/cyc/CU). So move the 576 gather instrs/block to the LDS pipe:
// stage an 8-row window [r0, r0+8) of xt[b] (131 KB -> 139 KB padded) with
// 128 coalesced VMEM instrs; samples read LDS (ds pipe, parallel to TA).
// N(0,1) offsets: ~0.8% of samples fall outside -> predicated global
// fallback (execz-skipped most iterations). TA/block: 128 stage + 288 A +
// ~30 fallback ~= 450 instr (vs 864). sRed aliases the window (dead after
// K-loop). 153 KB LDS -> 1 block/CU, 4 waves. No K-loop barriers.
// ---------------------------------------------------------------------------
__global__ __launch_bounds__(256, 1) void deform_kernel(const unsigned short* __restrict__ xt,
                                                        const float* __restrict__ off,
                                                        const unsigned short* __restrict__ wf,
                                                        float* __restrict__ out) {
  // window: [r][p][c] bytes, p-stride 272 (16B pad), r-stride 64*272=17408
  __shared__ __align__(16) unsigned char sWin[8 * 17408];   // 139264 B
  __shared__ int2   sPos[576];        // [tap*64+wo] row0/row1 position indices
  __shared__ float4 sWt[576];         // [tap*64+wo] folded bilinear weights

  const int tid = threadIdx.x;
  const int bid = blockIdx.x;
  const int b  = bid & 7;             // XCD-affine batch
  const int ho = bid >> 3;
  const int r0 = min(max(ho - 4, 0), 56);   // window base row

  // --- precompute sampling addresses + separable folded weights ---
  for (int r = tid; r < 576; r += 256) {
    int tap = r >> 6, wo = r & 63;
    float dy = off[((b * 18 + 2 * tap)     * 64 + ho) * 64 + wo];
    float dx = off[((b * 18 + 2 * tap + 1) * 64 + ho) * 64 + wo];
    float py = (float)(ho + (tap / 3) - 1) + dy;
    float px = (float)(wo + (tap % 3) - 1) + dx;
    float fy = floorf(py), fx = floorf(px);
    int y0 = (int)fy, x0 = (int)fx;
    float wy = py - fy, wx = px - fx;
    float wt = (y0 >= 0 && y0 < 64) ? (1.f - wy) : 0.f;
    float wb = (y0 + 1 >= 0 && y0 + 1 < 64) ? wy : 0.f;
    int y0c = min(max(y0, 0), 63), y1c = min(max(y0 + 1, 0), 63);
    int bx; float wl, wr;
    if (x0 >= 0 && x0 <= 62)      { bx = x0; wl = 1.f - wx; wr = wx;       }
    else if (x0 == -1)            { bx = 0;  wl = wx;       wr = 0.f;      }
    else if (x0 == 63)            { bx = 62; wl = 0.f;      wr = 1.f - wx; }
    else                          { bx = 0;  wl = 0.f;      wr = 0.f;      }
    sPos[r] = make_int2(y0c * 64 + bx, y1c * 64 + bx);
    sWt[r]  = make_float4(wt * wl, wt * wr, wb * wl, wb * wr);
  }

  // --- stage window rows r0..r0+7 (coalesced 16B/lane; 128 wave-instrs) ---
  {
    const unsigned short* xrow = xt + ((size_t)b << 19) + ((size_t)r0 << 13);
#pragma unroll
    for (int it = 0; it < 32; ++it) {
      int idx = it * 256 + tid;          // 16B-chunk id, 0..8191
      int c = idx & 15;                  // 16B chunk within 256B record
      int p = (idx >> 4) & 63;
      int r = idx >> 10;
      u32x4 v;
      __builtin_memcpy(&v, xrow + (((size_t)(r * 64 + p)) << 7) + c * 8, 16);
      *reinterpret_cast<u32x4*>(&sWin[r * 17408 + p * 272 + c * 16]) = v;
    }
  }
  __syncthreads();

  const int l  = tid & 63;
  const int ks = tid >> 6;        // wave -> channel slab cc = ks
  const int ln = l & 15;
  const int kg = l >> 4;          // k-group (8 consecutive channels)
  const int koff = ks * 64 + kg * 16;   // byte offset of lane's channels in record

  const unsigned short* xtb = xt + ((size_t)b << 19) + ks * 32 + kg * 8;
  const unsigned short* wfb = wf + (size_t)l * 8;

  f32x4 acc[4][8] = {};   // [pos-group][m-tile]

  for (int tap = 0; tap < 9; ++tap) {
    const int ch = ks * 9 + tap;

    // A-fragments once per chunk, reused across 4 pos-groups
    s16x8 A[8];
    const unsigned short* wp = wfb + (size_t)(ch * 8) * 512;
#pragma unroll
    for (int mt = 0; mt < 8; ++mt)
      A[mt] = *reinterpret_cast<const s16x8*>(wp + (size_t)mt * 512);

#pragma unroll
    for (int pg = 0; pg < 4; ++pg) {
      const int wo = pg * 16 + ln;
      const int2   a  = sPos[tap * 64 + wo];
      const float4 wv = sWt[tap * 64 + wo];

      const int ty = a.x >> 6, tx = a.x & 63;
      const int by = a.y >> 6;
      const int twr = ty - r0, bwr = by - r0;
      const bool tin = (unsigned)twr < 8u;
      const bool bin = (unsigned)bwr < 8u;

      u32x4 T0, T1, B0, B1;
      {
        int laT = (tin ? twr : 0) * 17408 + tx * 272 + koff;
        __builtin_memcpy(&T0, &sWin[laT],       16);
        __builtin_memcpy(&T1, &sWin[laT + 272], 16);
        int laB = (bin ? bwr : 0) * 17408 + tx * 272 + koff;
        __builtin_memcpy(&B0, &sWin[laB],       16);
        __builtin_memcpy(&B1, &sWin[laB + 272], 16);
      }
      if (!tin) {   // rare (~0.8%/sample): out-of-window row -> global
        const unsigned short* p0 = xtb + ((size_t)a.x << 7);
        __builtin_memcpy(&T0, p0,       16);
        __builtin_memcpy(&T1, p0 + 128, 16);
      }
      if (!bin) {
        const unsigned short* p1 = xtb + ((size_t)a.y << 7);
        __builtin_memcpy(&B0, p1,       16);
        __builtin_memcpy(&B1, p1 + 128, 16);
      }

      u32x4 pk;
#pragma unroll
      for (int d = 0; d < 4; ++d) {
        float vl = wv.x * bf_lo(T0[d]) + wv.y * bf_lo(T1[d])
                 + wv.z * bf_lo(B0[d]) + wv.w * bf_lo(B1[d]);
        float vh = wv.x * bf_hi(T0[d]) + wv.y * bf_hi(T1[d])
                 + wv.z * bf_hi(B0[d]) + wv.w * bf_hi(B1[d]);
        pk[d] = f2bf(vl) | (f2bf(vh) << 16);
      }
      s16x8 bfrag;
      __builtin_memcpy(&bfrag, &pk, 16);

#pragma unroll
      for (int mt = 0; mt < 8; ++mt)
        acc[pg][mt] = __builtin_amdgcn_mfma_f32_16x16x32_bf16(A[mt], bfrag, acc[pg][mt], 0, 0, 0);
    }
  }

  // ---- epilogue: serial LDS tree-reduce of the 4 K-partials ----
  // sRed aliases sWin (window dead after K-loop; barrier below fences it).
  float* sRed = reinterpret_cast<float*>(sWin);   // [wo][132] floats
#define WR_LDS                                                                 \
  { _Pragma("unroll") for (int pg = 0; pg < 4; ++pg)                           \
    _Pragma("unroll") for (int mt = 0; mt < 8; ++mt)                           \
      *reinterpret_cast<f32x4*>(&sRed[(pg * 16 + ln) * 132 + mt * 16 + kg * 4]) = acc[pg][mt]; }
#define RD_LDS                                                                 \
  { _Pragma("unroll") for (int pg = 0; pg < 4; ++pg)                           \
    _Pragma("unroll") for (int mt = 0; mt < 8; ++mt) {                         \
      f32x4 v = *reinterpret_cast<const f32x4*>(&sRed[(pg * 16 + ln) * 132 + mt * 16 + kg * 4]); \
      acc[pg][mt] += v; } }

  __syncthreads();
  if (ks == 1) WR_LDS
  __syncthreads();
  if (ks == 0) RD_LDS
  __syncthreads();
  if (ks == 3) WR_LDS
  __syncthreads();
  if (ks == 2) RD_LDS
  __syncthreads();
  if (ks == 2) WR_LDS
  __syncthreads();
  if (ks == 0) {
    RD_LDS
#pragma unroll
    for (int pg = 0; pg < 4; ++pg)
#pragma unroll
      for (int mt = 0; mt < 8; ++mt)
#pragma unroll
        for (int rg = 0; rg < 4; ++rg) {
          int co = mt * 16 + kg * 4 + rg;
          out[((b * 128 + co) * 64 + ho) * 64 + pg * 16 + ln] = acc[pg][mt][rg];
        }
  }
#undef WR_LDS
#undef RD_LDS
}

extern "C" void kernel_launch(void* const* d_in, const int* in_sizes, int n_in,
                              void* d_out, int out_size, void* d_ws, size_t ws_size,
                              hipStream_t stream) {
  (void)in_sizes; (void)n_in; (void)out_size; (void)ws_size;
  const float* x   = (const float*)d_in[0];
  const float* off = (const float*)d_in[1];
  const float* w   = (const float*)d_in[2];
  float* out = (float*)d_out;
  unsigned short* xt = (unsigned short*)d_ws;                 // 8388608 B
  unsigned short* wf = (unsigned short*)d_ws + (8388608 / 2); // 294912 B

  xtrans_kernel<<<2048, 256, 0, stream>>>(x, xt);
  wtrans_kernel<<<72, 256, 0, stream>>>(w, wf);
  deform_kernel<<<512, 256, 0, stream>>>(xt, off, wf, out);
}